// Round 1
// baseline (383.370 us; speedup 1.0000x reference)
//
#include <hip/hip_runtime.h>
#include <math.h>

#define DD 1024
#define BB 16
#define GAMMA_C 0.1f

// ws layout (float offsets)
#define WS_W     0      // 40 softmax weights (64 slots)
#define WS_QK    64
#define WS_VO    65
#define WS_XMAX  96     // 16
#define WS_XMIN  112    // 16
#define WS_COEFF 128    // 16*32 = 512
#define WS_U     1024   // 2*16*1024
#define WS_V     33792  // 2*16*1024

__device__ __forceinline__ float wred_sum(float v){
  #pragma unroll
  for (int o = 32; o > 0; o >>= 1) v += __shfl_xor(v, o, 64);
  return v;
}
__device__ __forceinline__ float wred_max(float v){
  #pragma unroll
  for (int o = 32; o > 0; o >>= 1) v = fmaxf(v, __shfl_xor(v, o, 64));
  return v;
}
__device__ __forceinline__ float wred_min(float v){
  #pragma unroll
  for (int o = 32; o > 0; o >>= 1) v = fminf(v, __shfl_xor(v, o, 64));
  return v;
}

// ---------------- prep: softmax(beta), attn scalars, per-batch x min/max ----
__global__ void prep_kernel(const float* __restrict__ x, const float* __restrict__ beta,
                            const float* __restrict__ wq, const float* __restrict__ wk,
                            const float* __restrict__ wv, const float* __restrict__ wo,
                            float* __restrict__ ws){
  int tid = threadIdx.x;
  int b = tid >> 6, lane = tid & 63;   // 16 waves, one per batch row
  float mx = -1e30f, mn = 1e30f;
  for (int j = lane; j < DD; j += 64){
    float v = x[b*DD + j];
    mx = fmaxf(mx, v); mn = fminf(mn, v);
  }
  mx = wred_max(mx); mn = wred_min(mn);
  if (lane == 0){ ws[WS_XMAX + b] = mx; ws[WS_XMIN + b] = mn; }
  if (tid == 0){
    float m = -1e30f;
    for (int k = 0; k < 40; k++) m = fmaxf(m, beta[k]);
    float e[40]; float s = 0.f;
    for (int k = 0; k < 40; k++){ e[k] = __expf(beta[k] - m); s += e[k]; }
    float inv = 1.f / s;
    for (int k = 0; k < 40; k++) ws[WS_W + k] = e[k] * inv;
    float qk = 0.f, vo = 0.f;
    for (int a = 0; a < 8; a++){ qk += wq[a]*wk[a]; vo += wv[a]*wo[a]; }
    ws[WS_QK] = qk; ws[WS_VO] = vo;
  }
}

// ---------------- elementwise + stencil ops (k = 0..31), writes residual ----
__global__ void elem_kernel(const float* __restrict__ x, const float* __restrict__ ws,
                            float* __restrict__ out){
  int idx = blockIdx.x * 256 + threadIdx.x;
  int b = idx / DD, i = idx - b*DD;
  const float* xr = x + b*DD;
  const float* w = ws + WS_W;
  float c = xr[i];
  float l = xr[i > 0 ? i-1 : 0];
  float r = xr[i < DD-1 ? i+1 : DD-1];
  float lap = l - 2.f*c + r;
  float s = 0.f;
  // RFF sin/cos, scales 0.5,1,2,4  (k0..7)
  s += w[0]*__sinf(0.5f*c) + w[1]*__sinf(c) + w[2]*__sinf(2.f*c) + w[3]*__sinf(4.f*c);
  s += w[4]*__cosf(0.5f*c) + w[5]*__cosf(c) + w[6]*__cosf(2.f*c) + w[7]*__cosf(4.f*c);
  // gelu (tanh approx, jax default), tanh, sigmoid (k8..10)
  {
    float inner = 0.7978845608028654f * (c + 0.044715f*c*c*c);
    s += w[8] * 0.5f*c*(1.f + tanhf(inner));
    s += w[9] * tanhf(c);
    s += w[10] * (1.f / (1.f + __expf(-c)));
  }
  // poly (k11..13)
  { float c2 = c*c; s += w[11]*c2 + w[12]*c2*c + w[13]*c2*c2; }
  // rational (k14..16)
  {
    float ac = fabsf(c);
    s += w[14]*(c/(1.001f + 0.5f*ac)) + w[15]*(c/(1.001f + ac)) + w[16]*(c/(1.001f + 2.f*ac));
  }
  // diffusion (k17..20)
  s += w[17]*(c + 0.001f*lap) + w[18]*(c + 0.003f*lap)
     + w[19]*(c + 0.01f*lap)  + w[20]*(c + 0.03f*lap);
  // blur (zero-padded conv) sigmas 0.5,1,2 -> r = 2,3,6 (k21..23)
  {
    const float sig[3] = {0.5f, 1.f, 2.f};
    const int   rr[3]  = {2, 3, 6};
    #pragma unroll
    for (int si = 0; si < 3; si++){
      float acc = 0.f, ksum = 0.f;
      for (int t = -rr[si]; t <= rr[si]; t++){
        float u = (float)t / sig[si];
        float kt = __expf(-0.5f*u*u);
        ksum += kt;
        int j = i + t;
        float xv = (j >= 0 && j < DD) ? xr[j] : 0.f;
        acc += kt * xv;
      }
      s += w[21 + si] * (acc / ksum);
    }
  }
  // 3-point LSE, taus 0.5,1,2,4 (k24..27)
  {
    const float taus[4] = {0.5f, 1.f, 2.f, 4.f};
    float m3 = fmaxf(l, fmaxf(c, r));
    #pragma unroll
    for (int ti = 0; ti < 4; ti++){
      float invt = 1.f / taus[ti];
      float e = __expf((l-m3)*invt) + __expf((c-m3)*invt) + __expf((r-m3)*invt);
      s += w[24 + ti] * (m3 + taus[ti]*__logf(e));
    }
  }
  // neighbor softmax, taus 0.5,1,2,4 (k28..31)
  {
    const float taus[4] = {0.5f, 1.f, 2.f, 4.f};
    float dl = fabsf(l - c), dr = fabsf(r - c);
    #pragma unroll
    for (int ti = 0; ti < 4; ti++){
      float invt = 1.f / taus[ti];
      float wl = __expf(-dl*invt), wr = __expf(-dr*invt);
      s += w[28 + ti] * ((wl*l + c + wr*r) / (wl + 1.f + wr));
    }
  }
  out[idx] = c + GAMMA_C * s;
}

// ---------------- RBF: d2 to prototypes -> coeff[b][p] (k32..34 folded) -----
__global__ void rbf_kernel(const float* __restrict__ x, const float* __restrict__ proto,
                           float* __restrict__ ws){
  int wid = blockIdx.x*4 + (threadIdx.x >> 6);
  int lane = threadIdx.x & 63;
  int b = wid >> 5, p = wid & 31;
  const float* xr = x + b*DD;
  const float* pr = proto + p*DD;
  float s = 0.f;
  for (int d = lane; d < DD; d += 64){
    float df = xr[d] - pr[d];
    s += df*df;
  }
  s = wred_sum(s);
  if (lane == 0){
    // 1/(2*sigma^2) for sigma = 0.5, 1, 2
    float cf = ws[WS_W+32]*__expf(-s*2.0f)
             + ws[WS_W+33]*__expf(-s*0.5f)
             + ws[WS_W+34]*__expf(-s*0.125f);
    ws[WS_COEFF + b*32 + p] = cf;
  }
}

// ---------------- attention (rank-1 collapse), taus 0.5 & 1 (k35,36) --------
__global__ void attn_kernel(const float* __restrict__ x, const float* __restrict__ ws,
                            float* __restrict__ out){
  __shared__ float xs[DD];
  int b = blockIdx.x >> 8;
  int chunk = blockIdx.x & 255;
  int tid = threadIdx.x;
  for (int t = tid; t < DD; t += 256) xs[t] = x[b*DD + t];
  __syncthreads();
  int wid = tid >> 6, lane = tid & 63;
  int i = chunk*4 + wid;
  float xi = xs[i];
  float qk = ws[WS_QK], vo = ws[WS_VO];
  const float inv_sqrt8 = 0.35355339059327373f;
  float a0 = qk * inv_sqrt8 * 2.f * xi;   // tau = 0.5
  float a1 = qk * inv_sqrt8 * xi;         // tau = 1
  float xmx = ws[WS_XMAX + b], xmn = ws[WS_XMIN + b];
  float m0 = (a0 >= 0.f) ? a0*xmx : a0*xmn;
  float m1 = (a1 >= 0.f) ? a1*xmx : a1*xmn;
  float s10 = 0.f, s20 = 0.f, s11 = 0.f, s21 = 0.f;
  for (int j = lane; j < DD; j += 64){
    float xj = xs[j];
    float e0 = __expf(a0*xj - m0);
    float e1 = __expf(a1*xj - m1);
    s10 += e0; s20 += e0*xj;
    s11 += e1; s21 += e1*xj;
  }
  s10 = wred_sum(s10); s20 = wred_sum(s20);
  s11 = wred_sum(s11); s21 = wred_sum(s21);
  if (lane == 0){
    float y0 = vo * s20 / s10;
    float y1 = vo * s21 / s11;
    out[b*DD + i] += GAMMA_C * (ws[WS_W+35]*y0 + ws[WS_W+36]*y1);
  }
}

// ---------------- Sinkhorn LSE sweep: out_i = LSE_j(-(xi-xj)^2/tau - in_j) --
__global__ void sink_lse_kernel(const float* __restrict__ x, const float* __restrict__ in,
                                float* __restrict__ outv, int has_in){
  __shared__ float xs[DD];
  __shared__ float vin[DD];
  int tau = blockIdx.x >> 12;
  int rest = blockIdx.x & 4095;
  int b = rest >> 8;
  int chunk = rest & 255;
  int tid = threadIdx.x;
  const float* inb = in + tau*(BB*DD) + b*DD;
  for (int t = tid; t < DD; t += 256){
    xs[t] = x[b*DD + t];
    vin[t] = has_in ? inb[t] : 0.f;
  }
  __syncthreads();
  int wid = tid >> 6, lane = tid & 63;
  int i = chunk*4 + wid;
  float xi = xs[i];
  float invtau = (tau == 0) ? 2.f : 1.f;
  float m = -1e30f;
  for (int j = lane; j < DD; j += 64){
    float d = xi - xs[j];
    float v = -d*d*invtau - vin[j];
    m = fmaxf(m, v);
  }
  m = wred_max(m);
  float s = 0.f;
  for (int j = lane; j < DD; j += 64){
    float d = xi - xs[j];
    float v = -d*d*invtau - vin[j];
    s += __expf(v - m);
  }
  s = wred_sum(s);
  if (lane == 0) outv[tau*(BB*DD) + b*DD + i] = m + __logf(s);
}

// ---------------- Sinkhorn apply: out_i += sum_j exp(la0-U-V)*x_j (k37,38) --
__global__ void sink_final_kernel(const float* __restrict__ x, const float* __restrict__ ws,
                                  float* __restrict__ out){
  __shared__ float xs[DD];
  __shared__ float v0[DD];
  __shared__ float v1[DD];
  int b = blockIdx.x >> 8;
  int chunk = blockIdx.x & 255;
  int tid = threadIdx.x;
  const float* U = ws + WS_U;
  const float* V = ws + WS_V;
  for (int t = tid; t < DD; t += 256){
    xs[t] = x[b*DD + t];
    v0[t] = V[b*DD + t];
    v1[t] = V[BB*DD + b*DD + t];
  }
  __syncthreads();
  int wid = tid >> 6, lane = tid & 63;
  int i = chunk*4 + wid;
  float xi = xs[i];
  float u0 = U[b*DD + i], u1 = U[BB*DD + b*DD + i];
  float s0 = 0.f, s1 = 0.f;
  for (int j = lane; j < DD; j += 64){
    float d = xi - xs[j];
    float d2 = d*d;
    float xj = xs[j];
    s0 += __expf(-d2*2.f - u0 - v0[j]) * xj;   // tau=0.5
    s1 += __expf(-d2      - u1 - v1[j]) * xj;  // tau=1
  }
  s0 = wred_sum(s0); s1 = wred_sum(s1);
  if (lane == 0) out[b*DD + i] += GAMMA_C * (ws[WS_W+37]*s0 + ws[WS_W+38]*s1);
}

// ---------------- linear (x @ W^T + b) + RBF projection add (k39 + k32..34) -
__global__ void linear_rbf_kernel(const float* __restrict__ x, const float* __restrict__ W,
                                  const float* __restrict__ bl, const float* __restrict__ proj,
                                  const float* __restrict__ ws, float* __restrict__ out){
  __shared__ float Wt[64][17];   // [d][i] transposed tile, padded
  __shared__ float xt[16][64];   // [b][d]
  int i0 = blockIdx.x * 16;
  int tid = threadIdx.x;
  int ii = tid & 15, b = tid >> 4;
  float acc = 0.f;
  for (int dc = 0; dc < 16; dc++){
    int d0 = dc * 64;
    __syncthreads();
    for (int e = tid; e < 1024; e += 256){
      int row = e >> 6, col = e & 63;
      Wt[col][row] = W[(i0 + row)*DD + d0 + col];
    }
    for (int e = tid; e < 1024; e += 256){
      int bb = e >> 6, col = e & 63;
      xt[bb][col] = x[bb*DD + d0 + col];
    }
    __syncthreads();
    #pragma unroll
    for (int dd = 0; dd < 64; dd++) acc += xt[b][dd] * Wt[dd][ii];
  }
  int i = i0 + ii;
  float val = acc + bl[i];
  float rb = 0.f;
  const float* coeff = ws + WS_COEFF + b*32;
  #pragma unroll
  for (int p = 0; p < 32; p++) rb += coeff[p] * proj[p*DD + i];
  out[b*DD + i] += GAMMA_C * (ws[WS_W+39]*val + rb);
}

extern "C" void kernel_launch(void* const* d_in, const int* in_sizes, int n_in,
                              void* d_out, int out_size, void* d_ws, size_t ws_size,
                              hipStream_t stream){
  const float* x     = (const float*)d_in[0];
  const float* beta  = (const float*)d_in[1];
  const float* W     = (const float*)d_in[2];
  const float* bl    = (const float*)d_in[3];
  const float* wq    = (const float*)d_in[4];
  const float* wk    = (const float*)d_in[5];
  const float* wv    = (const float*)d_in[6];
  const float* wo    = (const float*)d_in[7];
  const float* proto = (const float*)d_in[8];
  const float* proj  = (const float*)d_in[9];
  float* out = (float*)d_out;
  float* ws  = (float*)d_ws;
  float* U = ws + WS_U;
  float* V = ws + WS_V;

  prep_kernel<<<1, 1024, 0, stream>>>(x, beta, wq, wk, wv, wo, ws);
  elem_kernel<<<(BB*DD)/256, 256, 0, stream>>>(x, ws, out);
  rbf_kernel<<<(BB*32)/4, 256, 0, stream>>>(x, proto, ws);
  attn_kernel<<<BB*256, 256, 0, stream>>>(x, ws, out);

  // Sinkhorn: U,V,U,V,... 10 sweeps (5 iterations), both taus per launch
  sink_lse_kernel<<<2*BB*256, 256, 0, stream>>>(x, U, U, 0);           // U1 (V=0)
  for (int t = 0; t < 4; t++){
    sink_lse_kernel<<<2*BB*256, 256, 0, stream>>>(x, U, V, 1);         // V
    sink_lse_kernel<<<2*BB*256, 256, 0, stream>>>(x, V, U, 1);         // U
  }
  sink_lse_kernel<<<2*BB*256, 256, 0, stream>>>(x, U, V, 1);           // V5
  sink_final_kernel<<<BB*256, 256, 0, stream>>>(x, ws, out);

  linear_rbf_kernel<<<DD/16, 256, 0, stream>>>(x, W, bl, proj, ws, out);
}

// Round 2
// 346.071 us; speedup vs baseline: 1.1078x; 1.1078x over previous
//
#include <hip/hip_runtime.h>
#include <math.h>

#define DD 1024
#define BB 16
#define GAMMA_C 0.1f

// ws layout (float offsets)
#define WS_COEFF 0        // 16*32 rbf coefficients
#define WS_ATTN  512      // 16*1024 attn contribution (already gamma*w-scaled)
#define WS_U     20480    // 2*16*1024
#define WS_V     53248    // 2*16*1024

__device__ __forceinline__ float wred_sum(float v){
  #pragma unroll
  for (int o = 32; o > 0; o >>= 1) v += __shfl_xor(v, o, 64);
  return v;
}
__device__ __forceinline__ float wred_max(float v){
  #pragma unroll
  for (int o = 32; o > 0; o >>= 1) v = fmaxf(v, __shfl_xor(v, o, 64));
  return v;
}
__device__ __forceinline__ float wred_min(float v){
  #pragma unroll
  for (int o = 32; o > 0; o >>= 1) v = fminf(v, __shfl_xor(v, o, 64));
  return v;
}

// Per-block softmax(beta) -> w_s[0..39] in LDS (wave 0 does it, ~30 cyc).
// Contains __syncthreads(); call from all threads of the block.
__device__ __forceinline__ void block_softmax(const float* __restrict__ beta,
                                              float* w_s){
  int tid = threadIdx.x;
  if (tid < 64){
    float b = (tid < 40) ? beta[tid] : -3.0e38f;
    float m = wred_max(b);
    float e = (tid < 40) ? __expf(b - m) : 0.f;
    float s = wred_sum(e);
    if (tid < 40) w_s[tid] = e / s;
  }
  __syncthreads();
}

// =====================  fused A  ============================================
// blocks [0,64):    elem ops (k0..31), writes out = x + gamma*s
// blocks [64,192):  rbf coeff (k32..34 folded), writes ws[WS_COEFF]
// blocks [192,704): attention (k35,36), writes ws[WS_ATTN]
// blocks [704,1728): sinkhorn U1 sweep (V=0), writes ws[WS_U]
__global__ __launch_bounds__(256) void fused_a(
    const float* __restrict__ x, const float* __restrict__ beta,
    const float* __restrict__ wq, const float* __restrict__ wk,
    const float* __restrict__ wv, const float* __restrict__ wo,
    const float* __restrict__ proto, float* __restrict__ out,
    float* __restrict__ ws){
  __shared__ float xs[DD];
  __shared__ float w_s[40];
  int blk = blockIdx.x, tid = threadIdx.x;
  int wid = tid >> 6, lane = tid & 63;

  if (blk < 64){
    // ---------------- elementwise + stencil ops ----------------
    block_softmax(beta, w_s);
    int idx = blk*256 + tid;
    int b = idx >> 10, i = idx & 1023;
    const float* xr = x + b*DD;
    const float* w = w_s;
    float c = xr[i];
    float l = xr[i > 0 ? i-1 : 0];
    float r = xr[i < DD-1 ? i+1 : DD-1];
    float lap = l - 2.f*c + r;
    float s = 0.f;
    s += w[0]*__sinf(0.5f*c) + w[1]*__sinf(c) + w[2]*__sinf(2.f*c) + w[3]*__sinf(4.f*c);
    s += w[4]*__cosf(0.5f*c) + w[5]*__cosf(c) + w[6]*__cosf(2.f*c) + w[7]*__cosf(4.f*c);
    {
      float inner = 0.7978845608028654f * (c + 0.044715f*c*c*c);
      s += w[8] * 0.5f*c*(1.f + tanhf(inner));
      s += w[9] * tanhf(c);
      s += w[10] * (1.f / (1.f + __expf(-c)));
    }
    { float c2 = c*c; s += w[11]*c2 + w[12]*c2*c + w[13]*c2*c2; }
    {
      float ac = fabsf(c);
      s += w[14]*(c/(1.001f + 0.5f*ac)) + w[15]*(c/(1.001f + ac)) + w[16]*(c/(1.001f + 2.f*ac));
    }
    s += w[17]*(c + 0.001f*lap) + w[18]*(c + 0.003f*lap)
       + w[19]*(c + 0.01f*lap)  + w[20]*(c + 0.03f*lap);
    {
      const float sig[3] = {0.5f, 1.f, 2.f};
      const int   rr[3]  = {2, 3, 6};
      #pragma unroll
      for (int si = 0; si < 3; si++){
        float acc = 0.f, ksum = 0.f;
        for (int t = -rr[si]; t <= rr[si]; t++){
          float u = (float)t / sig[si];
          float kt = __expf(-0.5f*u*u);
          ksum += kt;
          int j = i + t;
          float xv = (j >= 0 && j < DD) ? xr[j] : 0.f;
          acc += kt * xv;
        }
        s += w[21 + si] * (acc / ksum);
      }
    }
    {
      const float taus[4] = {0.5f, 1.f, 2.f, 4.f};
      float m3 = fmaxf(l, fmaxf(c, r));
      #pragma unroll
      for (int ti = 0; ti < 4; ti++){
        float invt = 1.f / taus[ti];
        float e = __expf((l-m3)*invt) + __expf((c-m3)*invt) + __expf((r-m3)*invt);
        s += w[24 + ti] * (m3 + taus[ti]*__logf(e));
      }
    }
    {
      const float taus[4] = {0.5f, 1.f, 2.f, 4.f};
      float dl = fabsf(l - c), dr = fabsf(r - c);
      #pragma unroll
      for (int ti = 0; ti < 4; ti++){
        float invt = 1.f / taus[ti];
        float wl = __expf(-dl*invt), wr = __expf(-dr*invt);
        s += w[28 + ti] * ((wl*l + c + wr*r) / (wl + 1.f + wr));
      }
    }
    out[idx] = c + GAMMA_C * s;

  } else if (blk < 192){
    // ---------------- rbf distances -> coeff ----------------
    block_softmax(beta, w_s);
    int gw = (blk-64)*4 + wid;
    int b = gw >> 5, p = gw & 31;
    const float4* xr = (const float4*)(x + b*DD);
    const float4* pr = (const float4*)(proto + p*DD);
    float s = 0.f;
    #pragma unroll
    for (int k = 0; k < 4; k++){
      float4 a = xr[lane + 64*k], q = pr[lane + 64*k];
      float d0=a.x-q.x, d1=a.y-q.y, d2=a.z-q.z, d3=a.w-q.w;
      s += d0*d0 + d1*d1 + d2*d2 + d3*d3;
    }
    s = wred_sum(s);
    if (lane == 0){
      float cf = w_s[32]*__expf(-s*2.0f)
               + w_s[33]*__expf(-s*0.5f)
               + w_s[34]*__expf(-s*0.125f);
      ws[WS_COEFF + b*32 + p] = cf;
    }

  } else if (blk < 704){
    // ---------------- attention (rank-1 collapse; e0 = e1^2) ----------------
    int sb = blk - 192;
    int b = sb >> 5, chunk = sb & 31;
    ((float4*)xs)[tid] = ((const float4*)(x + b*DD))[tid];
    block_softmax(beta, w_s);   // sync also covers xs staging
    // per-wave scalars
    float tq = (lane < 8) ? wq[lane]*wk[lane] : 0.f;
    float tv = (lane < 8) ? wv[lane]*wo[lane] : 0.f;
    float qk = wred_sum(tq);
    float vo = wred_sum(tv);
    float mx = -3.0e38f, mn = 3.0e38f;
    #pragma unroll
    for (int k = 0; k < 16; k++){
      float v = xs[lane + 64*k];
      mx = fmaxf(mx, v); mn = fminf(mn, v);
    }
    mx = wred_max(mx); mn = wred_min(mn);
    const float inv_sqrt8 = 0.35355339059327373f;
    for (int t = 0; t < 8; t++){
      int i = chunk*32 + wid*8 + t;
      float xi = xs[i];
      float a1 = qk * inv_sqrt8 * xi;          // tau = 1 exponent coeff
      float m1 = (a1 >= 0.f) ? a1*mx : a1*mn;
      float s1 = 0.f, sx1 = 0.f, s2 = 0.f, sx2 = 0.f;
      #pragma unroll 4
      for (int k = 0; k < 16; k++){
        float xj = xs[lane + 64*k];
        float e1 = __expf(a1*xj - m1);
        float e2 = e1*e1;                       // == exp(a0*xj - 2*m1), a0=2*a1
        s1 += e1; sx1 += e1*xj;
        s2 += e2; sx2 += e2*xj;
      }
      s1 = wred_sum(s1); sx1 = wred_sum(sx1);
      s2 = wred_sum(s2); sx2 = wred_sum(sx2);
      if (lane == 0){
        float y0 = vo * sx2 / s2;   // tau = 0.5
        float y1 = vo * sx1 / s1;   // tau = 1
        ws[WS_ATTN + b*DD + i] = GAMMA_C * (w_s[35]*y0 + w_s[36]*y1);
      }
    }

  } else {
    // ---------------- sinkhorn U1 sweep (V = 0) ----------------
    int sb = blk - 704;
    int tau = sb >> 9, b = (sb >> 5) & 15, chunk = sb & 31;
    ((float4*)xs)[tid] = ((const float4*)(x + b*DD))[tid];
    __syncthreads();
    float invtau = (tau == 0) ? 2.f : 1.f;
    for (int t = 0; t < 8; t++){
      int i = chunk*32 + wid*8 + t;
      float xi = xs[i];
      float m = -3.0e38f;
      #pragma unroll 4
      for (int k = 0; k < 16; k++){
        float d = xi - xs[lane + 64*k];
        m = fmaxf(m, -d*d*invtau);
      }
      m = wred_max(m);
      float s = 0.f;
      #pragma unroll 4
      for (int k = 0; k < 16; k++){
        float d = xi - xs[lane + 64*k];
        s += __expf(-d*d*invtau - m);
      }
      s = wred_sum(s);
      if (lane == 0) ws[WS_U + tau*(BB*DD) + b*DD + i] = m + __logf(s);
    }
  }
}

// =====================  sinkhorn sweep  =====================================
// out_i = LSE_j( -(xi-xj)^2*invtau - in_j ), per (tau,b); grid 1024 blocks
__global__ __launch_bounds__(256) void sink_sweep(
    const float* __restrict__ x, const float* __restrict__ in,
    float* __restrict__ outv){
  __shared__ float xs[DD];
  __shared__ float vin[DD];
  int sb = blockIdx.x, tid = threadIdx.x;
  int wid = tid >> 6, lane = tid & 63;
  int tau = sb >> 9, b = (sb >> 5) & 15, chunk = sb & 31;
  ((float4*)xs)[tid]  = ((const float4*)(x + b*DD))[tid];
  ((float4*)vin)[tid] = ((const float4*)(in + tau*(BB*DD) + b*DD))[tid];
  __syncthreads();
  float invtau = (tau == 0) ? 2.f : 1.f;
  for (int t = 0; t < 8; t++){
    int i = chunk*32 + wid*8 + t;
    float xi = xs[i];
    float m = -3.0e38f;
    #pragma unroll 4
    for (int k = 0; k < 16; k++){
      int j = lane + 64*k;
      float d = xi - xs[j];
      m = fmaxf(m, -d*d*invtau - vin[j]);
    }
    m = wred_max(m);
    float s = 0.f;
    #pragma unroll 4
    for (int k = 0; k < 16; k++){
      int j = lane + 64*k;
      float d = xi - xs[j];
      s += __expf(-d*d*invtau - vin[j] - m);
    }
    s = wred_sum(s);
    if (lane == 0) outv[tau*(BB*DD) + b*DD + i] = m + __logf(s);
  }
}

// =====================  fused B  ============================================
// blocks [0,512):    sinkhorn apply (k37,38) -> atomicAdd out
// blocks [512,4608): linear + rbf-proj + attn-add (k39, k32..34) -> atomicAdd out
__global__ __launch_bounds__(256) void fused_b(
    const float* __restrict__ x, const float* __restrict__ beta,
    const float* __restrict__ W, const float* __restrict__ bl,
    const float* __restrict__ proj, float* __restrict__ out,
    float* __restrict__ ws){
  __shared__ float xs[DD];
  __shared__ float v0[DD];
  __shared__ float v1[DD];
  __shared__ float w_s[40];
  int blk = blockIdx.x, tid = threadIdx.x;
  int wid = tid >> 6, lane = tid & 63;

  if (blk < 512){
    // ---------------- sinkhorn apply ----------------
    int b = blk >> 5, chunk = blk & 31;
    const float* U = ws + WS_U;
    const float* V = ws + WS_V;
    ((float4*)xs)[tid] = ((const float4*)(x + b*DD))[tid];
    ((float4*)v0)[tid] = ((const float4*)(V + b*DD))[tid];
    ((float4*)v1)[tid] = ((const float4*)(V + BB*DD + b*DD))[tid];
    block_softmax(beta, w_s);   // sync covers staging
    for (int t = 0; t < 8; t++){
      int i = chunk*32 + wid*8 + t;
      float xi = xs[i];
      float u0 = U[b*DD + i], u1 = U[BB*DD + b*DD + i];
      float s0 = 0.f, s1 = 0.f;
      #pragma unroll 4
      for (int k = 0; k < 16; k++){
        int j = lane + 64*k;
        float xj = xs[j];
        float d = xi - xj;
        float d2 = d*d;
        s0 += __expf(-d2*2.f - u0 - v0[j]) * xj;   // tau = 0.5
        s1 += __expf(-d2     - u1 - v1[j]) * xj;   // tau = 1
      }
      s0 = wred_sum(s0); s1 = wred_sum(s1);
      if (lane == 0)
        atomicAdd(out + b*DD + i, GAMMA_C * (w_s[37]*s0 + w_s[38]*s1));
    }

  } else {
    // ---------------- linear (x @ W^T + b) + proj + attn add ----------------
    block_softmax(beta, w_s);
    int gw = (blk - 512)*4 + wid;
    int b = gw & 15, i = gw >> 4;     // consecutive waves share W row i
    const float4* Wr = (const float4*)(W + (size_t)i*DD);
    const float4* xr = (const float4*)(x + b*DD);
    float p = 0.f;
    #pragma unroll
    for (int k = 0; k < 4; k++){
      float4 a = Wr[lane + 64*k], c = xr[lane + 64*k];
      p += a.x*c.x + a.y*c.y + a.z*c.z + a.w*c.w;
    }
    float w39 = w_s[39];
    float tcontrib = w39 * p;
    if (lane < 32)
      tcontrib += ws[WS_COEFF + b*32 + lane] * proj[lane*DD + i];
    tcontrib = wred_sum(tcontrib);
    if (lane == 0){
      float v = GAMMA_C * (tcontrib + w39 * bl[i]) + ws[WS_ATTN + b*DD + i];
      atomicAdd(out + b*DD + i, v);
    }
  }
}

extern "C" void kernel_launch(void* const* d_in, const int* in_sizes, int n_in,
                              void* d_out, int out_size, void* d_ws, size_t ws_size,
                              hipStream_t stream){
  const float* x     = (const float*)d_in[0];
  const float* beta  = (const float*)d_in[1];
  const float* W     = (const float*)d_in[2];
  const float* bl    = (const float*)d_in[3];
  const float* wq    = (const float*)d_in[4];
  const float* wk    = (const float*)d_in[5];
  const float* wv    = (const float*)d_in[6];
  const float* wo    = (const float*)d_in[7];
  const float* proto = (const float*)d_in[8];
  const float* proj  = (const float*)d_in[9];
  float* out = (float*)d_out;
  float* ws  = (float*)d_ws;
  float* U = ws + WS_U;
  float* V = ws + WS_V;

  // elem + rbf + attn + sinkhorn-U1 in one launch
  fused_a<<<1728, 256, 0, stream>>>(x, beta, wq, wk, wv, wo, proto, out, ws);

  // 9 alternating sweeps: V1,U2,V2,U3,V3,U4,V4,U5,V5
  float* src = U; float* dst = V;
  for (int k = 0; k < 9; k++){
    sink_sweep<<<1024, 256, 0, stream>>>(x, src, dst);
    float* tmp = src; src = dst; dst = tmp;
  }

  // sinkhorn-apply + linear(+proj+attn) in one launch
  fused_b<<<4608, 256, 0, stream>>>(x, beta, W, bl, proj, out, ws);
}

// Round 3
// 175.965 us; speedup vs baseline: 2.1787x; 1.9667x over previous
//
#include <hip/hip_runtime.h>
#include <math.h>

#define DD 1024
#define BB 16
#define GAMMA_C 0.1f

// ws layout (float offsets)
#define WS_COEFF 0        // 16*32 rbf coefficients
#define WS_ATTN  512      // 16*1024 attn contribution (already gamma*w-scaled)
#define WS_U     20480    // 2*16*1024
#define WS_V     53248    // 2*16*1024

__device__ __forceinline__ float wred_sum(float v){
  #pragma unroll
  for (int o = 32; o > 0; o >>= 1) v += __shfl_xor(v, o, 64);
  return v;
}
__device__ __forceinline__ float wred_max(float v){
  #pragma unroll
  for (int o = 32; o > 0; o >>= 1) v = fmaxf(v, __shfl_xor(v, o, 64));
  return v;
}
__device__ __forceinline__ float wred_min(float v){
  #pragma unroll
  for (int o = 32; o > 0; o >>= 1) v = fminf(v, __shfl_xor(v, o, 64));
  return v;
}

// Per-block softmax(beta) -> w_s[0..39] in LDS. Contains __syncthreads().
__device__ __forceinline__ void block_softmax(const float* __restrict__ beta,
                                              float* w_s){
  int tid = threadIdx.x;
  if (tid < 64){
    float b = (tid < 40) ? beta[tid] : -3.0e38f;
    float m = wred_max(b);
    float e = (tid < 40) ? __expf(b - m) : 0.f;
    float s = wred_sum(e);
    if (tid < 40) w_s[tid] = e / s;
  }
  __syncthreads();
}

// load 16 consecutive-packed values: lane owns flat j = 4*(lane+64k)+c
__device__ __forceinline__ void load16(const float* __restrict__ p, int lane, float* r){
  const float4* p4 = (const float4*)p;
  #pragma unroll
  for (int k = 0; k < 4; k++){
    float4 a = p4[lane + 64*k];
    r[4*k+0] = a.x; r[4*k+1] = a.y; r[4*k+2] = a.z; r[4*k+3] = a.w;
  }
}

// =====================  fused A  ============================================
// blocks [0,64):    elem ops (k0..31), writes out = x + gamma*s
// blocks [64,192):  rbf coeff (k32..34 folded), writes ws[WS_COEFF]
// blocks [192,704): attention (k35,36), writes ws[WS_ATTN]
// blocks [704,1728): sinkhorn U1 sweep (V=0), writes ws[WS_U]
__global__ __launch_bounds__(256) void fused_a(
    const float* __restrict__ x, const float* __restrict__ beta,
    const float* __restrict__ wq, const float* __restrict__ wk,
    const float* __restrict__ wv, const float* __restrict__ wo,
    const float* __restrict__ proto, float* __restrict__ out,
    float* __restrict__ ws){
  __shared__ float xs[DD];
  __shared__ float w_s[40];
  int blk = blockIdx.x, tid = threadIdx.x;
  int wid = tid >> 6, lane = tid & 63;

  if (blk < 64){
    // ---------------- elementwise + stencil ops ----------------
    block_softmax(beta, w_s);
    int idx = blk*256 + tid;
    int b = idx >> 10, i = idx & 1023;
    const float* xr = x + b*DD;
    const float* w = w_s;
    float c = xr[i];
    float l = xr[i > 0 ? i-1 : 0];
    float r = xr[i < DD-1 ? i+1 : DD-1];
    float lap = l - 2.f*c + r;
    float s = 0.f;
    s += w[0]*__sinf(0.5f*c) + w[1]*__sinf(c) + w[2]*__sinf(2.f*c) + w[3]*__sinf(4.f*c);
    s += w[4]*__cosf(0.5f*c) + w[5]*__cosf(c) + w[6]*__cosf(2.f*c) + w[7]*__cosf(4.f*c);
    {
      float inner = 0.7978845608028654f * (c + 0.044715f*c*c*c);
      s += w[8] * 0.5f*c*(1.f + tanhf(inner));
      s += w[9] * tanhf(c);
      s += w[10] * (1.f / (1.f + __expf(-c)));
    }
    { float c2 = c*c; s += w[11]*c2 + w[12]*c2*c + w[13]*c2*c2; }
    {
      float ac = fabsf(c);
      s += w[14]*(c/(1.001f + 0.5f*ac)) + w[15]*(c/(1.001f + ac)) + w[16]*(c/(1.001f + 2.f*ac));
    }
    s += w[17]*(c + 0.001f*lap) + w[18]*(c + 0.003f*lap)
       + w[19]*(c + 0.01f*lap)  + w[20]*(c + 0.03f*lap);
    // blur, zero-padded, normalized gaussian taps precomputed
    {
      float acc = w[21] * 0.786572f * c;
      {
        const float k1 = 0.106452f, k2 = 2.63876e-4f;
        float s1 = 0.f;
        s1 += k1 * ((i>=1 ? xr[i-1]:0.f) + (i<DD-1 ? xr[i+1]:0.f));
        s1 += k2 * ((i>=2 ? xr[i-2]:0.f) + (i<DD-2 ? xr[i+2]:0.f));
        acc += w[21] * s1;
      }
      {
        const float t1 = 0.242036f, t2 = 0.0540056f, t3 = 0.00443305f;
        float s1 = 0.399050f * c;
        s1 += t1 * ((i>=1 ? xr[i-1]:0.f) + (i<DD-1 ? xr[i+1]:0.f));
        s1 += t2 * ((i>=2 ? xr[i-2]:0.f) + (i<DD-2 ? xr[i+2]:0.f));
        s1 += t3 * ((i>=3 ? xr[i-3]:0.f) + (i<DD-3 ? xr[i+3]:0.f));
        acc += w[22] * s1;
      }
      {
        const float g[7] = {0.199676f, 0.176216f, 0.121100f, 0.064825f,
                            0.027023f, 0.0087731f, 0.0022182f};
        float s1 = g[0] * c;
        #pragma unroll
        for (int t = 1; t <= 6; t++)
          s1 += g[t] * ((i>=t ? xr[i-t]:0.f) + (i<DD-t ? xr[i+t]:0.f));
        acc += w[23] * s1;
      }
      s += acc;
    }
    {
      const float taus[4] = {0.5f, 1.f, 2.f, 4.f};
      float m3 = fmaxf(l, fmaxf(c, r));
      #pragma unroll
      for (int ti = 0; ti < 4; ti++){
        float invt = 1.f / taus[ti];
        float e = __expf((l-m3)*invt) + __expf((c-m3)*invt) + __expf((r-m3)*invt);
        s += w[24 + ti] * (m3 + taus[ti]*__logf(e));
      }
    }
    {
      const float taus[4] = {0.5f, 1.f, 2.f, 4.f};
      float dl = fabsf(l - c), dr = fabsf(r - c);
      #pragma unroll
      for (int ti = 0; ti < 4; ti++){
        float invt = 1.f / taus[ti];
        float wl = __expf(-dl*invt), wr = __expf(-dr*invt);
        s += w[28 + ti] * ((wl*l + c + wr*r) / (wl + 1.f + wr));
      }
    }
    out[idx] = c + GAMMA_C * s;

  } else if (blk < 192){
    // ---------------- rbf distances -> coeff ----------------
    block_softmax(beta, w_s);
    int gw = (blk-64)*4 + wid;
    int b = gw >> 5, p = gw & 31;
    const float4* xr = (const float4*)(x + b*DD);
    const float4* pr = (const float4*)(proto + p*DD);
    float s = 0.f;
    #pragma unroll
    for (int k = 0; k < 4; k++){
      float4 a = xr[lane + 64*k], q = pr[lane + 64*k];
      float d0=a.x-q.x, d1=a.y-q.y, d2=a.z-q.z, d3=a.w-q.w;
      s += d0*d0 + d1*d1 + d2*d2 + d3*d3;
    }
    s = wred_sum(s);
    if (lane == 0){
      float cf = w_s[32]*__expf(-s*2.0f)
               + w_s[33]*__expf(-s*0.5f)
               + w_s[34]*__expf(-s*0.125f);
      ws[WS_COEFF + b*32 + p] = cf;
    }

  } else if (blk < 704){
    // ---------------- attention (rank-1 collapse; e0 = e1^2) ----------------
    int sb = blk - 192;
    int b = sb >> 5, chunk = sb & 31;
    ((float4*)xs)[tid] = ((const float4*)(x + b*DD))[tid];
    float xj[16];
    load16(x + b*DD, lane, xj);
    block_softmax(beta, w_s);   // sync also covers xs staging
    float tq = (lane < 8) ? wq[lane]*wk[lane] : 0.f;
    float tv = (lane < 8) ? wv[lane]*wo[lane] : 0.f;
    float qk = wred_sum(tq);
    float vo = wred_sum(tv);
    float mx = -3.0e38f, mn = 3.0e38f;
    #pragma unroll
    for (int k = 0; k < 16; k++){
      mx = fmaxf(mx, xj[k]); mn = fminf(mn, xj[k]);
    }
    mx = wred_max(mx); mn = wred_min(mn);
    const float inv_sqrt8 = 0.35355339059327373f;
    for (int t = 0; t < 8; t++){
      int i = chunk*32 + wid*8 + t;
      float xi = xs[i];
      float a1 = qk * inv_sqrt8 * xi;          // tau = 1 exponent coeff
      float m1 = (a1 >= 0.f) ? a1*mx : a1*mn;
      float s1 = 0.f, sx1 = 0.f, s2 = 0.f, sx2 = 0.f;
      #pragma unroll
      for (int k = 0; k < 16; k++){
        float e1 = __expf(fmaf(a1, xj[k], -m1));
        float e2 = e1*e1;                       // == exp(a0*xj - 2*m1)
        s1 += e1; sx1 = fmaf(e1, xj[k], sx1);
        s2 += e2; sx2 = fmaf(e2, xj[k], sx2);
      }
      s1 = wred_sum(s1); sx1 = wred_sum(sx1);
      s2 = wred_sum(s2); sx2 = wred_sum(sx2);
      if (lane == 0){
        float y0 = vo * sx2 / s2;   // tau = 0.5
        float y1 = vo * sx1 / s1;   // tau = 1
        ws[WS_ATTN + b*DD + i] = GAMMA_C * (w_s[35]*y0 + w_s[36]*y1);
      }
    }

  } else {
    // ---------------- sinkhorn U1 sweep (V = 0), factored, no max pass -----
    int sb = blk - 704;
    int tau = sb >> 9, b = (sb >> 5) & 15, chunk = sb & 31;
    ((float4*)xs)[tid] = ((const float4*)(x + b*DD))[tid];
    float invtau = (tau == 0) ? 2.f : 1.f;
    float xj[16], cj[16];
    load16(x + b*DD, lane, xj);
    #pragma unroll
    for (int k = 0; k < 16; k++) cj[k] = -invtau*xj[k]*xj[k];
    __syncthreads();
    float ti2 = 2.f*invtau;
    for (int t = 0; t < 8; t++){
      int i = chunk*32 + wid*8 + t;
      float xi = xs[i];
      float ki = ti2*xi;
      float ai = -invtau*xi*xi;
      float s = 0.f;
      #pragma unroll
      for (int k = 0; k < 16; k++) s += __expf(fmaf(ki, xj[k], cj[k]));
      s = wred_sum(s);
      if (lane == 0) ws[WS_U + tau*(BB*DD) + b*DD + i] = ai + __logf(s);
    }
  }
}

// =====================  sinkhorn sweep  =====================================
// out_i = LSE_j( -(xi-xj)^2*invtau - in_j ), factored single pass
__global__ __launch_bounds__(256) void sink_sweep(
    const float* __restrict__ x, const float* __restrict__ in,
    float* __restrict__ outv){
  __shared__ float xs[DD];
  int sb = blockIdx.x, tid = threadIdx.x;
  int wid = tid >> 6, lane = tid & 63;
  int tau = sb >> 9, b = (sb >> 5) & 15, chunk = sb & 31;
  ((float4*)xs)[tid] = ((const float4*)(x + b*DD))[tid];
  float invtau = (tau == 0) ? 2.f : 1.f;
  float xj[16], cj[16];
  load16(x + b*DD, lane, xj);
  {
    float vj[16];
    load16(in + tau*(BB*DD) + b*DD, lane, vj);
    #pragma unroll
    for (int k = 0; k < 16; k++) cj[k] = fmaf(-invtau*xj[k], xj[k], -vj[k]);
  }
  __syncthreads();
  float ti2 = 2.f*invtau;
  for (int t = 0; t < 8; t++){
    int i = chunk*32 + wid*8 + t;
    float xi = xs[i];
    float ki = ti2*xi;
    float ai = -invtau*xi*xi;
    float s = 0.f;
    #pragma unroll
    for (int k = 0; k < 16; k++) s += __expf(fmaf(ki, xj[k], cj[k]));
    s = wred_sum(s);
    if (lane == 0) outv[tau*(BB*DD) + b*DD + i] = ai + __logf(s);
  }
}

// =====================  fused B  ============================================
// blocks [0,512):    sinkhorn apply (k37,38) -> atomicAdd out
// blocks [512,1536): linear + rbf-proj + attn-add -> atomicAdd out (4 b/wave)
__global__ __launch_bounds__(256) void fused_b(
    const float* __restrict__ x, const float* __restrict__ beta,
    const float* __restrict__ W, const float* __restrict__ bl,
    const float* __restrict__ proj, float* __restrict__ out,
    float* __restrict__ ws){
  __shared__ float xs[DD];
  __shared__ float w_s[40];
  int blk = blockIdx.x, tid = threadIdx.x;
  int wid = tid >> 6, lane = tid & 63;

  if (blk < 512){
    // ---------------- sinkhorn apply, factored ----------------
    int b = blk >> 5, chunk = blk & 31;
    const float* U = ws + WS_U;
    const float* V = ws + WS_V;
    ((float4*)xs)[tid] = ((const float4*)(x + b*DD))[tid];
    float xj[16], c0[16], c1[16];
    load16(x + b*DD, lane, xj);
    {
      float v0[16], v1[16];
      load16(V + b*DD, lane, v0);
      load16(V + BB*DD + b*DD, lane, v1);
      #pragma unroll
      for (int k = 0; k < 16; k++){
        float x2 = xj[k]*xj[k];
        c0[k] = fmaf(-2.f, x2, -v0[k]);
        c1[k] = -x2 - v1[k];
      }
    }
    block_softmax(beta, w_s);   // sync covers xs staging
    for (int t = 0; t < 8; t++){
      int i = chunk*32 + wid*8 + t;
      float xi = xs[i];
      float u0 = U[b*DD + i], u1 = U[BB*DD + b*DD + i];
      float k0 = 4.f*xi, k1 = 2.f*xi;
      float a0 = fmaf(-2.f*xi, xi, -u0);
      float a1 = fmaf(-xi, xi, -u1);
      float s0 = 0.f, s1 = 0.f;
      #pragma unroll
      for (int k = 0; k < 16; k++){
        float e0 = __expf(fmaf(k0, xj[k], c0[k]));
        float e1 = __expf(fmaf(k1, xj[k], c1[k]));
        s0 = fmaf(e0, xj[k], s0);
        s1 = fmaf(e1, xj[k], s1);
      }
      s0 = wred_sum(s0); s1 = wred_sum(s1);
      if (lane == 0){
        float r = w_s[37]*__expf(a0)*s0 + w_s[38]*__expf(a1)*s1;
        atomicAdd(out + b*DD + i, GAMMA_C * r);
      }
    }

  } else {
    // ---------------- linear (x @ W^T + b) + proj + attn add ---------------
    // block handles one i; 4 waves x 4 batches each
    block_softmax(beta, w_s);
    int i = blk - 512;
    float Wv[16];
    load16(W + (size_t)i*DD, lane, Wv);
    float projv = (lane < 32) ? proj[lane*DD + i] : 0.f;
    float w39 = w_s[39];
    float blv = bl[i];
    #pragma unroll
    for (int bq = 0; bq < 4; bq++){
      int b = wid*4 + bq;
      float xv[16];
      load16(x + b*DD, lane, xv);
      float p = 0.f;
      #pragma unroll
      for (int k = 0; k < 16; k++) p = fmaf(Wv[k], xv[k], p);
      float t = w39 * p;
      if (lane < 32) t = fmaf(ws[WS_COEFF + b*32 + lane], projv, t);
      t = wred_sum(t);
      if (lane == 0){
        float v = GAMMA_C * (t + w39 * blv) + ws[WS_ATTN + b*DD + i];
        atomicAdd(out + b*DD + i, v);
      }
    }
  }
}

extern "C" void kernel_launch(void* const* d_in, const int* in_sizes, int n_in,
                              void* d_out, int out_size, void* d_ws, size_t ws_size,
                              hipStream_t stream){
  const float* x     = (const float*)d_in[0];
  const float* beta  = (const float*)d_in[1];
  const float* W     = (const float*)d_in[2];
  const float* bl    = (const float*)d_in[3];
  const float* wq    = (const float*)d_in[4];
  const float* wk    = (const float*)d_in[5];
  const float* wv    = (const float*)d_in[6];
  const float* wo    = (const float*)d_in[7];
  const float* proto = (const float*)d_in[8];
  const float* proj  = (const float*)d_in[9];
  float* out = (float*)d_out;
  float* ws  = (float*)d_ws;
  float* U = ws + WS_U;
  float* V = ws + WS_V;

  // elem + rbf + attn + sinkhorn-U1 in one launch
  fused_a<<<1728, 256, 0, stream>>>(x, beta, wq, wk, wv, wo, proto, out, ws);

  // 9 alternating sweeps: V1,U2,V2,U3,V3,U4,V4,U5,V5
  float* src = U; float* dst = V;
  for (int k = 0; k < 9; k++){
    sink_sweep<<<1024, 256, 0, stream>>>(x, src, dst);
    float* tmp = src; src = dst; dst = tmp;
  }

  // sinkhorn-apply + linear(+proj+attn) in one launch
  fused_b<<<1536, 256, 0, stream>>>(x, beta, W, bl, proj, out, ws);
}